// Round 1
// baseline (382.993 us; speedup 1.0000x reference)
//
#include <hip/hip_runtime.h>

#define IN_CH 128
#define OUT_CH 32
#define HEADS 8
#define HC 256            // HEADS*OUT_CH
#define NEG_SLOPE 0.2f

// ---------------- Projection GEMM + per-node attention logits ----------------
// Block: 256 threads, each thread owns one output column t (of 256).
// Each block computes 16 rows. x rows are read via block-uniform addresses
// (scalar cache), W via coalesced vector loads (L2-resident, 128 KB).
__global__ __launch_bounds__(256)
void gat_proj(const float* __restrict__ x, const float* __restrict__ W,
              const float* __restrict__ attS, const float* __restrict__ attD,
              float* __restrict__ h, float* __restrict__ aS, float* __restrict__ aD,
              int N)
{
    const int t = threadIdx.x;
    const int row0 = blockIdx.x * 16;
    float acc[16];
#pragma unroll
    for (int r = 0; r < 16; ++r) acc[r] = 0.f;

    const float* xr = x + (size_t)row0 * IN_CH;   // block-uniform base
#pragma unroll 4
    for (int c = 0; c < IN_CH; ++c) {
        const float wv = W[c * HC + t];           // coalesced, L2-hot
#pragma unroll
        for (int r = 0; r < 16; ++r)
            acc[r] = fmaf(xr[r * IN_CH + c], wv, acc[r]);  // uniform -> s_load
    }

    const float asw = attS[t];   // att_src[head][c] with t = head*32 + c
    const float adw = attD[t];
#pragma unroll
    for (int r = 0; r < 16; ++r) {
        const int row = row0 + r;
        if (row < N) {
            h[(size_t)row * HC + t] = acc[r];
            float ps = acc[r] * asw;
            float pd = acc[r] * adw;
            // reduce within each 32-lane channel group (= one head)
#pragma unroll
            for (int off = 1; off < 32; off <<= 1) {
                ps += __shfl_xor(ps, off, 64);
                pd += __shfl_xor(pd, off, 64);
            }
            if ((t & 31) == 0) {
                aS[row * HEADS + (t >> 5)] = ps;
                aD[row * HEADS + (t >> 5)] = pd;
            }
        }
    }
}

// ---------------- CSR build: histogram -> scan -> scatter ----------------
__global__ void gat_hist(const int* __restrict__ dst, int* __restrict__ counts, int E)
{
    const int e = blockIdx.x * blockDim.x + threadIdx.x;
    if (e < E) atomicAdd(&counts[dst[e]], 1);
}

__global__ __launch_bounds__(1024)
void gat_scan(const int* __restrict__ counts, int* __restrict__ offsets,
              int* __restrict__ cursor, int n)
{
    __shared__ int wsums[16];
    __shared__ int carry_s;
    const int t = threadIdx.x;
    const int lane = t & 63;
    const int wid = t >> 6;
    if (t == 0) carry_s = 0;
    __syncthreads();

    for (int base = 0; base < n; base += 1024) {
        const int idx = base + t;
        const int v = (idx < n) ? counts[idx] : 0;
        int inc = v;
#pragma unroll
        for (int off = 1; off < 64; off <<= 1) {
            int y = __shfl_up(inc, off, 64);
            if (lane >= off) inc += y;
        }
        if (lane == 63) wsums[wid] = inc;
        __syncthreads();
        if (t < 16) {
            const int wv = wsums[t];
            int winc = wv;
#pragma unroll
            for (int off = 1; off < 16; off <<= 1) {
                int y = __shfl_up(winc, off, 64);
                if (t >= off) winc += y;
            }
            wsums[t] = winc - wv;   // exclusive wave offset
        }
        __syncthreads();
        const int excl = carry_s + wsums[wid] + (inc - v);
        if (idx < n) { offsets[idx] = excl; cursor[idx] = excl; }
        __syncthreads();
        if (t == 1023) carry_s += wsums[15] + inc;
        __syncthreads();
    }
    if (t == 0) offsets[n] = carry_s;
}

__global__ void gat_scatter(const int* __restrict__ src, const int* __restrict__ dst,
                            int* __restrict__ cursor, int* __restrict__ ssrc, int E)
{
    const int e = blockIdx.x * blockDim.x + threadIdx.x;
    if (e < E) {
        const int pos = atomicAdd(&cursor[dst[e]], 1);
        ssrc[pos] = src[e];
    }
}

// ---------------- Per-node softmax + aggregation (one wave per node) ----------------
__global__ __launch_bounds__(256)
void gat_agg(const float* __restrict__ h, const float* __restrict__ aS,
             const float* __restrict__ aD, const int* __restrict__ offsets,
             const int* __restrict__ ssrc, const float* __restrict__ bias,
             float* __restrict__ out, int N)
{
    const int t = threadIdx.x;
    const int lane = t & 63;
    const int node = blockIdx.x * 4 + (t >> 6);
    if (node >= N) return;

    const int head = lane >> 3;       // lane*4 channels -> head = lane/8
    const int ch = lane << 2;         // 4 channels per lane
    const float adv = aD[node * HEADS + head];

    // self loop logit
    float lg0 = aS[node * HEADS + head] + adv;
    lg0 = (lg0 > 0.f) ? lg0 : NEG_SLOPE * lg0;

    const int beg = offsets[node];
    const int end = offsets[node + 1];

    // pass 1: per-head max (all 8 lanes of a head group compute identically)
    float mx = lg0;
    for (int e = beg; e < end; ++e) {
        const int s = ssrc[e];
        float lg = aS[s * HEADS + head] + adv;
        lg = (lg > 0.f) ? lg : NEG_SLOPE * lg;
        mx = fmaxf(mx, lg);
    }

    // pass 2: exp-weighted accumulate
    float p = __expf(lg0 - mx);
    float sum = p;
    const float4 hv = *(const float4*)(h + (size_t)node * HC + ch);
    float4 acc = make_float4(p * hv.x, p * hv.y, p * hv.z, p * hv.w);

    for (int e = beg; e < end; ++e) {
        const int s = ssrc[e];
        float lg = aS[s * HEADS + head] + adv;
        lg = (lg > 0.f) ? lg : NEG_SLOPE * lg;
        const float pe = __expf(lg - mx);
        sum += pe;
        const float4 sv = *(const float4*)(h + (size_t)s * HC + ch);
        acc.x = fmaf(pe, sv.x, acc.x);
        acc.y = fmaf(pe, sv.y, acc.y);
        acc.z = fmaf(pe, sv.z, acc.z);
        acc.w = fmaf(pe, sv.w, acc.w);
    }

    const float inv = 1.f / (sum + 1e-16f);
    const float4 bv = *(const float4*)(bias + ch);
    float4 o;
    o.x = fmaxf(fmaf(acc.x, inv, bv.x), 0.f);
    o.y = fmaxf(fmaf(acc.y, inv, bv.y), 0.f);
    o.z = fmaxf(fmaf(acc.z, inv, bv.z), 0.f);
    o.w = fmaxf(fmaf(acc.w, inv, bv.w), 0.f);
    *(float4*)(out + (size_t)node * HC + ch) = o;
}

extern "C" void kernel_launch(void* const* d_in, const int* in_sizes, int n_in,
                              void* d_out, int out_size, void* d_ws, size_t ws_size,
                              hipStream_t stream)
{
    const float* x    = (const float*)d_in[0];
    const int*   ei   = (const int*)d_in[1];
    const float* W    = (const float*)d_in[2];
    const float* attS = (const float*)d_in[3];
    const float* attD = (const float*)d_in[4];
    const float* bias = (const float*)d_in[5];
    float* out = (float*)d_out;

    const int N = in_sizes[0] / IN_CH;
    const int E = in_sizes[1] / 2;
    const int* esrc = ei;        // edge_index[0] = source j
    const int* edst = ei + E;    // edge_index[1] = destination i

    // workspace layout (all 4-byte types; h at 16B-aligned base)
    float* h  = (float*)d_ws;                       // N*256
    float* aS = h + (size_t)N * HC;                 // N*8
    float* aD = aS + (size_t)N * HEADS;             // N*8
    int* counts  = (int*)(aD + (size_t)N * HEADS);  // N
    int* offsets = counts + N;                      // N+1
    int* cursor  = offsets + (N + 1);               // N
    int* ssrc    = cursor + N;                      // E

    hipMemsetAsync(counts, 0, (size_t)N * sizeof(int), stream);

    gat_proj<<<(N + 15) / 16, 256, 0, stream>>>(x, W, attS, attD, h, aS, aD, N);
    gat_hist<<<(E + 255) / 256, 256, 0, stream>>>(edst, counts, E);
    gat_scan<<<1, 1024, 0, stream>>>(counts, offsets, cursor, N);
    gat_scatter<<<(E + 255) / 256, 256, 0, stream>>>(esrc, edst, cursor, ssrc, E);
    gat_agg<<<(N + 3) / 4, 256, 0, stream>>>(h, aS, aD, offsets, ssrc, bias, out, N);
}

// Round 2
// 299.021 us; speedup vs baseline: 1.2808x; 1.2808x over previous
//
#include <hip/hip_runtime.h>

#define IN_CH 128
#define OUT_CH 32
#define HEADS 8
#define HC 256            // HEADS*OUT_CH
#define NEG_SLOPE 0.2f

// bf16 helpers (bit-exact, RNE on store)
__device__ __forceinline__ float bflo(unsigned u) { return __uint_as_float(u << 16); }
__device__ __forceinline__ float bfhi(unsigned u) { return __uint_as_float(u & 0xffff0000u); }
__device__ __forceinline__ unsigned short f2bf(float f) {
    unsigned u = __float_as_uint(f);
    u = (u + 0x7fffu + ((u >> 16) & 1u)) >> 16;   // round-to-nearest-even
    return (unsigned short)u;
}

// ---------------- Projection GEMM + per-node attention logits ----------------
// Block: 256 threads, one output column each; 16 rows per block.
// x rows via block-uniform (scalar) loads, W coalesced (L2-hot, 128 KB).
// h stored in bf16 to halve the aggregation gather traffic.
__global__ __launch_bounds__(256)
void gat_proj(const float* __restrict__ x, const float* __restrict__ W,
              const float* __restrict__ attS, const float* __restrict__ attD,
              unsigned short* __restrict__ h, float* __restrict__ aS,
              float* __restrict__ aD, int N)
{
    const int t = threadIdx.x;
    const int row0 = blockIdx.x * 16;
    float acc[16];
#pragma unroll
    for (int r = 0; r < 16; ++r) acc[r] = 0.f;

    const float* xr = x + (size_t)row0 * IN_CH;   // block-uniform base
#pragma unroll 4
    for (int c = 0; c < IN_CH; ++c) {
        const float wv = W[c * HC + t];           // coalesced, L2-hot
#pragma unroll
        for (int r = 0; r < 16; ++r)
            acc[r] = fmaf(xr[r * IN_CH + c], wv, acc[r]);  // uniform -> s_load
    }

    const float asw = attS[t];   // att_src[head][c] with t = head*32 + c
    const float adw = attD[t];
#pragma unroll
    for (int r = 0; r < 16; ++r) {
        const int row = row0 + r;
        if (row < N) {
            h[(size_t)row * HC + t] = f2bf(acc[r]);
            float ps = acc[r] * asw;
            float pd = acc[r] * adw;
#pragma unroll
            for (int off = 1; off < 32; off <<= 1) {
                ps += __shfl_xor(ps, off, 64);
                pd += __shfl_xor(pd, off, 64);
            }
            if ((t & 31) == 0) {
                aS[row * HEADS + (t >> 5)] = ps;
                aD[row * HEADS + (t >> 5)] = pd;
            }
        }
    }
}

// ---------------- CSR build: histogram -> scan -> scatter ----------------
__global__ void gat_hist(const int* __restrict__ dst, int* __restrict__ counts, int E)
{
    const int e = blockIdx.x * blockDim.x + threadIdx.x;
    if (e < E) atomicAdd(&counts[dst[e]], 1);
}

__global__ __launch_bounds__(1024)
void gat_scan(const int* __restrict__ counts, int* __restrict__ offsets,
              int* __restrict__ cursor, int n)
{
    __shared__ int wsums[16];
    __shared__ int carry_s;
    const int t = threadIdx.x;
    const int lane = t & 63;
    const int wid = t >> 6;
    if (t == 0) carry_s = 0;
    __syncthreads();

    for (int base = 0; base < n; base += 1024) {
        const int idx = base + t;
        const int v = (idx < n) ? counts[idx] : 0;
        int inc = v;
#pragma unroll
        for (int off = 1; off < 64; off <<= 1) {
            int y = __shfl_up(inc, off, 64);
            if (lane >= off) inc += y;
        }
        if (lane == 63) wsums[wid] = inc;
        __syncthreads();
        if (t < 16) {
            const int wv = wsums[t];
            int winc = wv;
#pragma unroll
            for (int off = 1; off < 16; off <<= 1) {
                int y = __shfl_up(winc, off, 64);
                if (t >= off) winc += y;
            }
            wsums[t] = winc - wv;   // exclusive wave offset
        }
        __syncthreads();
        const int excl = carry_s + wsums[wid] + (inc - v);
        if (idx < n) { offsets[idx] = excl; cursor[idx] = excl; }
        __syncthreads();
        if (t == 1023) carry_s += wsums[15] + inc;
        __syncthreads();
    }
    if (t == 0) offsets[n] = carry_s;
}

__global__ void gat_scatter(const int* __restrict__ src, const int* __restrict__ dst,
                            int* __restrict__ cursor, int* __restrict__ ssrc, int E)
{
    const int e = blockIdx.x * blockDim.x + threadIdx.x;
    if (e < E) {
        const int pos = atomicAdd(&cursor[dst[e]], 1);
        ssrc[pos] = src[e];
    }
}

// ---------------- Per-node softmax + aggregation (one wave per node) ----------------
// Single pass: softmax is shift-invariant and logits are bounded (|e|<~10),
// so exp() without max-subtraction is exact in f32 here. h gathered as bf16.
__global__ __launch_bounds__(256)
void gat_agg(const unsigned short* __restrict__ h, const float* __restrict__ aS,
             const float* __restrict__ aD, const int* __restrict__ offsets,
             const int* __restrict__ ssrc, const float* __restrict__ bias,
             float* __restrict__ out, int N)
{
    const int t = threadIdx.x;
    const int lane = t & 63;
    const int node = blockIdx.x * 4 + (t >> 6);
    if (node >= N) return;

    const int head = lane >> 3;       // 8 lanes per head
    const int ch = lane << 2;         // 4 channels per lane
    const float adv = aD[node * HEADS + head];

    // self loop
    float lg0 = aS[node * HEADS + head] + adv;
    lg0 = (lg0 > 0.f) ? lg0 : NEG_SLOPE * lg0;
    float p = __expf(lg0);
    float sum = p;

    uint2 hv = *(const uint2*)(h + (size_t)node * HC + ch);
    float4 acc;
    acc.x = p * bflo(hv.x);
    acc.y = p * bfhi(hv.x);
    acc.z = p * bflo(hv.y);
    acc.w = p * bfhi(hv.y);

    const int beg = offsets[node];
    const int end = offsets[node + 1];
#pragma unroll 2
    for (int e = beg; e < end; ++e) {
        const int s = ssrc[e];                      // wave-uniform -> s_load
        float lg = aS[s * HEADS + head] + adv;
        lg = (lg > 0.f) ? lg : NEG_SLOPE * lg;
        const float pe = __expf(lg);
        sum += pe;
        const uint2 sv = *(const uint2*)(h + (size_t)s * HC + ch);
        acc.x = fmaf(pe, bflo(sv.x), acc.x);
        acc.y = fmaf(pe, bfhi(sv.x), acc.y);
        acc.z = fmaf(pe, bflo(sv.y), acc.z);
        acc.w = fmaf(pe, bfhi(sv.y), acc.w);
    }

    const float inv = 1.f / (sum + 1e-16f);
    const float4 bv = *(const float4*)(bias + ch);
    float4 o;
    o.x = fmaxf(fmaf(acc.x, inv, bv.x), 0.f);
    o.y = fmaxf(fmaf(acc.y, inv, bv.y), 0.f);
    o.z = fmaxf(fmaf(acc.z, inv, bv.z), 0.f);
    o.w = fmaxf(fmaf(acc.w, inv, bv.w), 0.f);
    *(float4*)(out + (size_t)node * HC + ch) = o;
}

extern "C" void kernel_launch(void* const* d_in, const int* in_sizes, int n_in,
                              void* d_out, int out_size, void* d_ws, size_t ws_size,
                              hipStream_t stream)
{
    const float* x    = (const float*)d_in[0];
    const int*   ei   = (const int*)d_in[1];
    const float* W    = (const float*)d_in[2];
    const float* attS = (const float*)d_in[3];
    const float* attD = (const float*)d_in[4];
    const float* bias = (const float*)d_in[5];
    float* out = (float*)d_out;

    const int N = in_sizes[0] / IN_CH;
    const int E = in_sizes[1] / 2;
    const int* esrc = ei;        // edge_index[0] = source j
    const int* edst = ei + E;    // edge_index[1] = destination i

    // workspace layout (h bf16 first, 16B-aligned base; N*HC*2 is 16B-multiple)
    unsigned short* h = (unsigned short*)d_ws;        // N*256 bf16
    float* aS = (float*)(h + (size_t)N * HC);         // N*8
    float* aD = aS + (size_t)N * HEADS;               // N*8
    int* counts  = (int*)(aD + (size_t)N * HEADS);    // N
    int* offsets = counts + N;                        // N+1
    int* cursor  = offsets + (N + 1);                 // N
    int* ssrc    = cursor + N;                        // E

    hipMemsetAsync(counts, 0, (size_t)N * sizeof(int), stream);

    gat_proj<<<(N + 15) / 16, 256, 0, stream>>>(x, W, attS, attD, h, aS, aD, N);
    gat_hist<<<(E + 255) / 256, 256, 0, stream>>>(edst, counts, E);
    gat_scan<<<1, 1024, 0, stream>>>(counts, offsets, cursor, N);
    gat_scatter<<<(E + 255) / 256, 256, 0, stream>>>(esrc, edst, cursor, ssrc, E);
    gat_agg<<<(N + 3) / 4, 256, 0, stream>>>(h, aS, aD, offsets, ssrc, bias, out, N);
}

// Round 3
// 257.297 us; speedup vs baseline: 1.4885x; 1.1622x over previous
//
#include <hip/hip_runtime.h>

#define IN_CH 128
#define OUT_CH 32
#define HEADS 8
#define HC 256            // HEADS*OUT_CH
#define NEG_SLOPE 0.2f

typedef __attribute__((ext_vector_type(8))) short short8;   // 8 bf16 = 4 VGPR
typedef __attribute__((ext_vector_type(4))) float f32x4;

// bf16 helpers (RNE)
__device__ __forceinline__ float bflo(unsigned u) { return __uint_as_float(u << 16); }
__device__ __forceinline__ float bfhi(unsigned u) { return __uint_as_float(u & 0xffff0000u); }
__device__ __forceinline__ unsigned short f2bf(float f) {
    unsigned u = __float_as_uint(f);
    u = (u + 0x7fffu + ((u >> 16) & 1u)) >> 16;
    return (unsigned short)u;
}

// ---------------- W transpose + f32->bf16 (once, 64 KB output) ----------------
__global__ __launch_bounds__(256)
void gat_prep(const float* __restrict__ W, unsigned short* __restrict__ Wt)
{
    const int idx = blockIdx.x * 256 + threadIdx.x;   // 32768 elements
    const int k = idx >> 8;          // 0..127
    const int col = idx & 255;       // 0..255
    Wt[col * IN_CH + k] = f2bf(W[idx]);
}

// ---------------- MFMA projection: h = x@W (bf16), + per-node logits ----------------
// Block: 256 threads = 4 waves; 16 rows x 256 cols per block.
// Wave w owns cols [w*64, w*64+64) = N-tiles i=0..3, heads {2w, 2w+1}.
__global__ __launch_bounds__(256)
void gat_proj_mfma(const float* __restrict__ x, const unsigned short* __restrict__ Wt,
                   const float* __restrict__ attS, const float* __restrict__ attD,
                   unsigned short* __restrict__ h, float* __restrict__ aS,
                   float* __restrict__ aD, int N)
{
    __shared__ unsigned short xs[16 * 136];   // 16 rows x 128 bf16, +8 pad/row

    const int tid = threadIdx.x;
    const int lane = tid & 63;
    const int w = tid >> 6;
    const int row0 = blockIdx.x * 16;

    // ---- preload B fragments (W_t, L2-hot): 16 x 16B per lane = 64 VGPR ----
    short8 bfr[4][4];   // [ks][i]
    {
        const unsigned short* wp = Wt + (size_t)(w * 64 + (lane & 15)) * IN_CH
                                      + ((lane >> 4) << 3);
#pragma unroll
        for (int i = 0; i < 4; ++i)
#pragma unroll
            for (int ks = 0; ks < 4; ++ks)
                bfr[ks][i] = *(const short8*)(wp + i * 16 * IN_CH + ks * 32);
    }

    // ---- stage x tile -> LDS bf16 (coalesced f32 reads) ----
    {
        const int srow = tid >> 4;          // 0..15
        const int sseg = tid & 15;          // 8 floats each
        const int grow = row0 + srow;
        float4 v0 = make_float4(0.f, 0.f, 0.f, 0.f), v1 = v0;
        if (grow < N) {
            const float* xp = x + (size_t)grow * IN_CH + sseg * 8;
            v0 = *(const float4*)xp;
            v1 = *(const float4*)(xp + 4);
        }
        unsigned short* lp = xs + srow * 136 + sseg * 8;
        lp[0] = f2bf(v0.x); lp[1] = f2bf(v0.y); lp[2] = f2bf(v0.z); lp[3] = f2bf(v0.w);
        lp[4] = f2bf(v1.x); lp[5] = f2bf(v1.y); lp[6] = f2bf(v1.z); lp[7] = f2bf(v1.w);
    }
    __syncthreads();

    // ---- K loop: 4 x (ds_read_b128 + 4 MFMA) ----
    f32x4 acc[4] = {{0.f,0.f,0.f,0.f},{0.f,0.f,0.f,0.f},{0.f,0.f,0.f,0.f},{0.f,0.f,0.f,0.f}};
#pragma unroll
    for (int ks = 0; ks < 4; ++ks) {
        const short8 a = *(const short8*)&xs[(lane & 15) * 136 + ks * 32 + ((lane >> 4) << 3)];
#pragma unroll
        for (int i = 0; i < 4; ++i)
            acc[i] = __builtin_amdgcn_mfma_f32_16x16x32_bf16(a, bfr[ks][i], acc[i], 0, 0, 0);
    }

    // ---- epilogue: h store (bf16) + logit partials ----
    // C/D map: col = lane&15, row = (lane>>4)*4 + reg   [m89-verified]
    const int rbase = (lane >> 4) << 2;
    float ps[2][4] = {{0.f,0.f,0.f,0.f},{0.f,0.f,0.f,0.f}};
    float pd[2][4] = {{0.f,0.f,0.f,0.f},{0.f,0.f,0.f,0.f}};
#pragma unroll
    for (int i = 0; i < 4; ++i) {
        const int col = w * 64 + i * 16 + (lane & 15);
        const int hp = i >> 1;
        const float asv = attS[(w * 2 + hp) * 32 + (i & 1) * 16 + (lane & 15)];
        const float adv = attD[(w * 2 + hp) * 32 + (i & 1) * 16 + (lane & 15)];
#pragma unroll
        for (int r = 0; r < 4; ++r) {
            const int grow = row0 + rbase + r;
            if (grow < N) h[(size_t)grow * HC + col] = f2bf(acc[i][r]);
            ps[hp][r] = fmaf(acc[i][r], asv, ps[hp][r]);
            pd[hp][r] = fmaf(acc[i][r], adv, pd[hp][r]);
        }
    }
    // reduce across the 16 lanes sharing this row group
#pragma unroll
    for (int off = 1; off < 16; off <<= 1) {
#pragma unroll
        for (int hp = 0; hp < 2; ++hp)
#pragma unroll
            for (int r = 0; r < 4; ++r) {
                ps[hp][r] += __shfl_xor(ps[hp][r], off, 64);
                pd[hp][r] += __shfl_xor(pd[hp][r], off, 64);
            }
    }
    if ((lane & 15) == 0) {
#pragma unroll
        for (int hp = 0; hp < 2; ++hp)
#pragma unroll
            for (int r = 0; r < 4; ++r) {
                const int grow = row0 + rbase + r;
                if (grow < N) {
                    aS[grow * HEADS + w * 2 + hp] = ps[hp][r];
                    aD[grow * HEADS + w * 2 + hp] = pd[hp][r];
                }
            }
    }
}

// ---------------- CSR build: histogram -> scan -> scatter ----------------
__global__ void gat_hist(const int* __restrict__ dst, int* __restrict__ counts, int E)
{
    const int e = blockIdx.x * blockDim.x + threadIdx.x;
    if (e < E) atomicAdd(&counts[dst[e]], 1);
}

__global__ __launch_bounds__(1024)
void gat_scan(const int* __restrict__ counts, int* __restrict__ offsets,
              int* __restrict__ cursor, int n)
{
    __shared__ int wsums[16];
    __shared__ int carry_s;
    const int t = threadIdx.x;
    const int lane = t & 63;
    const int wid = t >> 6;
    if (t == 0) carry_s = 0;
    __syncthreads();

    for (int base = 0; base < n; base += 1024) {
        const int idx = base + t;
        const int v = (idx < n) ? counts[idx] : 0;
        int inc = v;
#pragma unroll
        for (int off = 1; off < 64; off <<= 1) {
            int y = __shfl_up(inc, off, 64);
            if (lane >= off) inc += y;
        }
        if (lane == 63) wsums[wid] = inc;
        __syncthreads();
        if (t < 16) {
            const int wv = wsums[t];
            int winc = wv;
#pragma unroll
            for (int off = 1; off < 16; off <<= 1) {
                int y = __shfl_up(winc, off, 64);
                if (t >= off) winc += y;
            }
            wsums[t] = winc - wv;
        }
        __syncthreads();
        const int excl = carry_s + wsums[wid] + (inc - v);
        if (idx < n) { offsets[idx] = excl; cursor[idx] = excl; }
        __syncthreads();
        if (t == 1023) carry_s += wsums[15] + inc;
        __syncthreads();
    }
    if (t == 0) offsets[n] = carry_s;
}

__global__ void gat_scatter(const int* __restrict__ src, const int* __restrict__ dst,
                            int* __restrict__ cursor, int* __restrict__ ssrc, int E)
{
    const int e = blockIdx.x * blockDim.x + threadIdx.x;
    if (e < E) {
        const int pos = atomicAdd(&cursor[dst[e]], 1);
        ssrc[pos] = src[e];
    }
}

// ---------------- Per-node softmax + aggregation (one wave per node) ----------------
__global__ __launch_bounds__(256)
void gat_agg(const unsigned short* __restrict__ h, const float* __restrict__ aS,
             const float* __restrict__ aD, const int* __restrict__ offsets,
             const int* __restrict__ ssrc, const float* __restrict__ bias,
             float* __restrict__ out, int N)
{
    const int t = threadIdx.x;
    const int lane = t & 63;
    const int node = blockIdx.x * 4 + (t >> 6);
    if (node >= N) return;

    const int head = lane >> 3;
    const int ch = lane << 2;
    const float adv = aD[node * HEADS + head];

    float lg0 = aS[node * HEADS + head] + adv;
    lg0 = (lg0 > 0.f) ? lg0 : NEG_SLOPE * lg0;
    float p = __expf(lg0);
    float sum = p;

    uint2 hv = *(const uint2*)(h + (size_t)node * HC + ch);
    float4 acc;
    acc.x = p * bflo(hv.x);
    acc.y = p * bfhi(hv.x);
    acc.z = p * bflo(hv.y);
    acc.w = p * bfhi(hv.y);

    const int beg = offsets[node];
    const int end = offsets[node + 1];
#pragma unroll 2
    for (int e = beg; e < end; ++e) {
        const int s = ssrc[e];
        float lg = aS[s * HEADS + head] + adv;
        lg = (lg > 0.f) ? lg : NEG_SLOPE * lg;
        const float pe = __expf(lg);
        sum += pe;
        const uint2 sv = *(const uint2*)(h + (size_t)s * HC + ch);
        acc.x = fmaf(pe, bflo(sv.x), acc.x);
        acc.y = fmaf(pe, bfhi(sv.x), acc.y);
        acc.z = fmaf(pe, bflo(sv.y), acc.z);
        acc.w = fmaf(pe, bfhi(sv.y), acc.w);
    }

    const float inv = 1.f / (sum + 1e-16f);
    const float4 bv = *(const float4*)(bias + ch);
    float4 o;
    o.x = fmaxf(fmaf(acc.x, inv, bv.x), 0.f);
    o.y = fmaxf(fmaf(acc.y, inv, bv.y), 0.f);
    o.z = fmaxf(fmaf(acc.z, inv, bv.z), 0.f);
    o.w = fmaxf(fmaf(acc.w, inv, bv.w), 0.f);
    *(float4*)(out + (size_t)node * HC + ch) = o;
}

extern "C" void kernel_launch(void* const* d_in, const int* in_sizes, int n_in,
                              void* d_out, int out_size, void* d_ws, size_t ws_size,
                              hipStream_t stream)
{
    const float* x    = (const float*)d_in[0];
    const int*   ei   = (const int*)d_in[1];
    const float* W    = (const float*)d_in[2];
    const float* attS = (const float*)d_in[3];
    const float* attD = (const float*)d_in[4];
    const float* bias = (const float*)d_in[5];
    float* out = (float*)d_out;

    const int N = in_sizes[0] / IN_CH;
    const int E = in_sizes[1] / 2;
    const int* esrc = ei;        // edge_index[0] = source j
    const int* edst = ei + E;    // edge_index[1] = destination i

    // workspace layout
    unsigned short* h = (unsigned short*)d_ws;        // N*256 bf16
    float* aS = (float*)(h + (size_t)N * HC);         // N*8
    float* aD = aS + (size_t)N * HEADS;               // N*8
    int* counts  = (int*)(aD + (size_t)N * HEADS);    // N
    int* offsets = counts + N;                        // N+1
    int* cursor  = offsets + (N + 1);                 // N
    int* ssrc    = cursor + N;                        // E
    unsigned short* Wt = (unsigned short*)(ssrc + E); // 256*128 bf16

    hipMemsetAsync(counts, 0, (size_t)N * sizeof(int), stream);

    gat_prep<<<(IN_CH * HC) / 256, 256, 0, stream>>>(W, Wt);
    gat_proj_mfma<<<(N + 15) / 16, 256, 0, stream>>>(x, Wt, attS, attD, h, aS, aD, N);
    gat_hist<<<(E + 255) / 256, 256, 0, stream>>>(edst, counts, E);
    gat_scan<<<1, 1024, 0, stream>>>(counts, offsets, cursor, N);
    gat_scatter<<<(E + 255) / 256, 256, 0, stream>>>(esrc, edst, cursor, ssrc, E);
    gat_agg<<<(N + 3) / 4, 256, 0, stream>>>(h, aS, aD, offsets, ssrc, bias, out, N);
}

// Round 4
// 218.276 us; speedup vs baseline: 1.7546x; 1.1788x over previous
//
#include <hip/hip_runtime.h>

#define IN_CH 128
#define OUT_CH 32
#define HEADS 8
#define HC 256            // HEADS*OUT_CH
#define NEG_SLOPE 0.2f

typedef __attribute__((ext_vector_type(8))) short short8;   // 8 bf16 = 4 VGPR
typedef __attribute__((ext_vector_type(4))) float f32x4;

// bf16 helpers (RNE)
__device__ __forceinline__ float bflo(unsigned u) { return __uint_as_float(u << 16); }
__device__ __forceinline__ float bfhi(unsigned u) { return __uint_as_float(u & 0xffff0000u); }
__device__ __forceinline__ unsigned short f2bf(float f) {
    unsigned u = __float_as_uint(f);
    u = (u + 0x7fffu + ((u >> 16) & 1u)) >> 16;
    return (unsigned short)u;
}

// ---------------- W transpose + f32->bf16 (once, 64 KB output) ----------------
__global__ __launch_bounds__(256)
void gat_prep(const float* __restrict__ W, unsigned short* __restrict__ Wt)
{
    const int idx = blockIdx.x * 256 + threadIdx.x;   // 32768 elements
    const int k = idx >> 8;
    const int col = idx & 255;
    Wt[col * IN_CH + k] = f2bf(W[idx]);
}

// ---------------- MFMA projection: h = x@W (bf16), + per-node logits ----------------
__global__ __launch_bounds__(256)
void gat_proj_mfma(const float* __restrict__ x, const unsigned short* __restrict__ Wt,
                   const float* __restrict__ attS, const float* __restrict__ attD,
                   unsigned short* __restrict__ h, float* __restrict__ aS,
                   float* __restrict__ aD, int N)
{
    __shared__ unsigned short xs[16 * 136];

    const int tid = threadIdx.x;
    const int lane = tid & 63;
    const int w = tid >> 6;
    const int row0 = blockIdx.x * 16;

    short8 bfr[4][4];
    {
        const unsigned short* wp = Wt + (size_t)(w * 64 + (lane & 15)) * IN_CH
                                      + ((lane >> 4) << 3);
#pragma unroll
        for (int i = 0; i < 4; ++i)
#pragma unroll
            for (int ks = 0; ks < 4; ++ks)
                bfr[ks][i] = *(const short8*)(wp + i * 16 * IN_CH + ks * 32);
    }

    {
        const int srow = tid >> 4;
        const int sseg = tid & 15;
        const int grow = row0 + srow;
        float4 v0 = make_float4(0.f, 0.f, 0.f, 0.f), v1 = v0;
        if (grow < N) {
            const float* xp = x + (size_t)grow * IN_CH + sseg * 8;
            v0 = *(const float4*)xp;
            v1 = *(const float4*)(xp + 4);
        }
        unsigned short* lp = xs + srow * 136 + sseg * 8;
        lp[0] = f2bf(v0.x); lp[1] = f2bf(v0.y); lp[2] = f2bf(v0.z); lp[3] = f2bf(v0.w);
        lp[4] = f2bf(v1.x); lp[5] = f2bf(v1.y); lp[6] = f2bf(v1.z); lp[7] = f2bf(v1.w);
    }
    __syncthreads();

    f32x4 acc[4] = {{0.f,0.f,0.f,0.f},{0.f,0.f,0.f,0.f},{0.f,0.f,0.f,0.f},{0.f,0.f,0.f,0.f}};
#pragma unroll
    for (int ks = 0; ks < 4; ++ks) {
        const short8 a = *(const short8*)&xs[(lane & 15) * 136 + ks * 32 + ((lane >> 4) << 3)];
#pragma unroll
        for (int i = 0; i < 4; ++i)
            acc[i] = __builtin_amdgcn_mfma_f32_16x16x32_bf16(a, bfr[ks][i], acc[i], 0, 0, 0);
    }

    // C/D map: col = lane&15, row = (lane>>4)*4 + reg   [m89-verified]
    const int rbase = (lane >> 4) << 2;
    float ps[2][4] = {{0.f,0.f,0.f,0.f},{0.f,0.f,0.f,0.f}};
    float pd[2][4] = {{0.f,0.f,0.f,0.f},{0.f,0.f,0.f,0.f}};
#pragma unroll
    for (int i = 0; i < 4; ++i) {
        const int col = w * 64 + i * 16 + (lane & 15);
        const int hp = i >> 1;
        const float asv = attS[(w * 2 + hp) * 32 + (i & 1) * 16 + (lane & 15)];
        const float adv = attD[(w * 2 + hp) * 32 + (i & 1) * 16 + (lane & 15)];
#pragma unroll
        for (int r = 0; r < 4; ++r) {
            const int grow = row0 + rbase + r;
            if (grow < N) h[(size_t)grow * HC + col] = f2bf(acc[i][r]);
            ps[hp][r] = fmaf(acc[i][r], asv, ps[hp][r]);
            pd[hp][r] = fmaf(acc[i][r], adv, pd[hp][r]);
        }
    }
#pragma unroll
    for (int off = 1; off < 16; off <<= 1) {
#pragma unroll
        for (int hp = 0; hp < 2; ++hp)
#pragma unroll
            for (int r = 0; r < 4; ++r) {
                ps[hp][r] += __shfl_xor(ps[hp][r], off, 64);
                pd[hp][r] += __shfl_xor(pd[hp][r], off, 64);
            }
    }
    if ((lane & 15) == 0) {
#pragma unroll
        for (int hp = 0; hp < 2; ++hp)
#pragma unroll
            for (int r = 0; r < 4; ++r) {
                const int grow = row0 + rbase + r;
                if (grow < N) {
                    aS[grow * HEADS + w * 2 + hp] = ps[hp][r];
                    aD[grow * HEADS + w * 2 + hp] = pd[hp][r];
                }
            }
    }
}

// ---------------- CSR build: histogram -> 3-phase scan -> scatter ----------------
__global__ __launch_bounds__(256)
void gat_hist(const int* __restrict__ dst, int* __restrict__ counts, int E)
{
    int i = (blockIdx.x * 256 + threadIdx.x) * 4;
    if (i + 3 < E) {
        const int4 d = *(const int4*)&dst[i];
        atomicAdd(&counts[d.x], 1);
        atomicAdd(&counts[d.y], 1);
        atomicAdd(&counts[d.z], 1);
        atomicAdd(&counts[d.w], 1);
    } else {
        for (; i < E; ++i) atomicAdd(&counts[dst[i]], 1);
    }
}

// phase 1: per-1024-chunk block sums
__global__ __launch_bounds__(256)
void gat_scan1(const int* __restrict__ counts, int* __restrict__ bsum, int n)
{
    __shared__ int ws[4];
    const int t = threadIdx.x;
    const int lane = t & 63;
    const int wid = t >> 6;
    const int idx = blockIdx.x * 1024 + t * 4;
    int4 v = {0, 0, 0, 0};
    if (idx + 3 < n) v = *(const int4*)&counts[idx];
    else {
        if (idx < n)     v.x = counts[idx];
        if (idx + 1 < n) v.y = counts[idx + 1];
        if (idx + 2 < n) v.z = counts[idx + 2];
    }
    int s4 = v.x + v.y + v.z + v.w;
#pragma unroll
    for (int off = 1; off < 64; off <<= 1) s4 += __shfl_xor(s4, off, 64);
    if (lane == 0) ws[wid] = s4;
    __syncthreads();
    if (t == 0) bsum[blockIdx.x] = ws[0] + ws[1] + ws[2] + ws[3];
}

// phase 2: exclusive scan of block sums (single wave; nb <= 64)
__global__ void gat_scan2(int* __restrict__ bsum, int* __restrict__ offsets, int nb, int n)
{
    const int lane = threadIdx.x;
    const int v = (lane < nb) ? bsum[lane] : 0;
    int inc = v;
#pragma unroll
    for (int off = 1; off < 64; off <<= 1) {
        const int y = __shfl_up(inc, off, 64);
        if (lane >= off) inc += y;
    }
    if (lane < nb) bsum[lane] = inc - v;     // exclusive
    if (lane == 63) offsets[n] = inc;        // grand total = E
}

// phase 3: per-chunk scan + add block offset, write offsets & cursor
__global__ __launch_bounds__(256)
void gat_scan3(const int* __restrict__ counts, const int* __restrict__ bsum,
               int* __restrict__ offsets, int* __restrict__ cursor, int n)
{
    __shared__ int wsums[4];
    const int t = threadIdx.x;
    const int lane = t & 63;
    const int wid = t >> 6;
    const int idx = blockIdx.x * 1024 + t * 4;
    int4 v = {0, 0, 0, 0};
    if (idx + 3 < n) v = *(const int4*)&counts[idx];
    else {
        if (idx < n)     v.x = counts[idx];
        if (idx + 1 < n) v.y = counts[idx + 1];
        if (idx + 2 < n) v.z = counts[idx + 2];
    }
    const int s4 = v.x + v.y + v.z + v.w;
    int inc = s4;
#pragma unroll
    for (int off = 1; off < 64; off <<= 1) {
        const int y = __shfl_up(inc, off, 64);
        if (lane >= off) inc += y;
    }
    if (lane == 63) wsums[wid] = inc;
    __syncthreads();
    int wbase = 0;
    for (int i = 0; i < wid; ++i) wbase += wsums[i];
    const int base = bsum[blockIdx.x] + wbase + (inc - s4);
    int4 o;
    o.x = base;
    o.y = base + v.x;
    o.z = o.y + v.y;
    o.w = o.z + v.z;
    if (idx + 3 < n) {
        *(int4*)&offsets[idx] = o;
        *(int4*)&cursor[idx] = o;
    } else {
        if (idx < n)     { offsets[idx] = o.x;     cursor[idx] = o.x; }
        if (idx + 1 < n) { offsets[idx + 1] = o.y; cursor[idx + 1] = o.y; }
        if (idx + 2 < n) { offsets[idx + 2] = o.z; cursor[idx + 2] = o.z; }
    }
}

__global__ void gat_scatter(const int* __restrict__ src, const int* __restrict__ dst,
                            int* __restrict__ cursor, int* __restrict__ ssrc, int E)
{
    const int e = blockIdx.x * blockDim.x + threadIdx.x;
    if (e < E) {
        const int pos = atomicAdd(&cursor[dst[e]], 1);
        ssrc[pos] = src[e];
    }
}

// ---------------- Per-node softmax + aggregation ----------------
// One wave per node; two 32-lane halves each process a different edge per
// iteration (uint4 = 16 B/lane), doubling memory-level parallelism and
// halving redundant exp work. Cross-half combine via shfl_xor(32).
__global__ __launch_bounds__(256)
void gat_agg(const unsigned short* __restrict__ h, const float* __restrict__ aS,
             const float* __restrict__ aD, const int* __restrict__ offsets,
             const int* __restrict__ ssrc, const float* __restrict__ bias,
             float* __restrict__ out, int N)
{
    const int t = threadIdx.x;
    const int lane = t & 63;
    const int node = blockIdx.x * 4 + (t >> 6);
    if (node >= N) return;

    const int half = lane >> 5;
    const int hl = lane & 31;
    const int head = hl >> 2;                  // 4 lanes per head
    const int ch = head * 32 + (hl & 3) * 8;   // 8 channels per lane

    const float adv = aD[node * HEADS + head];

    float sum;
    float acc[8];
    {   // self loop (counted once, in half 0)
        float lg0 = aS[node * HEADS + head] + adv;
        lg0 = (lg0 > 0.f) ? lg0 : NEG_SLOPE * lg0;
        const float w0 = half ? 0.f : __expf(lg0);
        sum = w0;
        const uint4 hv = *(const uint4*)(h + (size_t)node * HC + ch);
        acc[0] = w0 * bflo(hv.x); acc[1] = w0 * bfhi(hv.x);
        acc[2] = w0 * bflo(hv.y); acc[3] = w0 * bfhi(hv.y);
        acc[4] = w0 * bflo(hv.z); acc[5] = w0 * bfhi(hv.z);
        acc[6] = w0 * bflo(hv.w); acc[7] = w0 * bfhi(hv.w);
    }

    const int beg = offsets[node];
    const int end = offsets[node + 1];
#pragma unroll 2
    for (int base = beg; base < end; base += 2) {
        const int e = base + half;
        const bool act = e < end;
        const int s = act ? ssrc[e] : node;
        float lg = aS[s * HEADS + head] + adv;
        lg = (lg > 0.f) ? lg : NEG_SLOPE * lg;
        const float pe = act ? __expf(lg) : 0.f;
        sum += pe;
        const uint4 sv = *(const uint4*)(h + (size_t)s * HC + ch);
        acc[0] = fmaf(pe, bflo(sv.x), acc[0]);
        acc[1] = fmaf(pe, bfhi(sv.x), acc[1]);
        acc[2] = fmaf(pe, bflo(sv.y), acc[2]);
        acc[3] = fmaf(pe, bfhi(sv.y), acc[3]);
        acc[4] = fmaf(pe, bflo(sv.z), acc[4]);
        acc[5] = fmaf(pe, bfhi(sv.z), acc[5]);
        acc[6] = fmaf(pe, bflo(sv.w), acc[6]);
        acc[7] = fmaf(pe, bfhi(sv.w), acc[7]);
    }

    // combine halves
#pragma unroll
    for (int j = 0; j < 8; ++j) acc[j] += __shfl_xor(acc[j], 32, 64);
    sum += __shfl_xor(sum, 32, 64);

    const float inv = 1.f / (sum + 1e-16f);
    const int cbase = ch + half * 4;       // each lane stores 4 of its 8 channels
    const int j0 = half * 4;
    const float4 bv = *(const float4*)(bias + cbase);
    float4 o;
    o.x = fmaxf(fmaf(acc[j0 + 0], inv, bv.x), 0.f);
    o.y = fmaxf(fmaf(acc[j0 + 1], inv, bv.y), 0.f);
    o.z = fmaxf(fmaf(acc[j0 + 2], inv, bv.z), 0.f);
    o.w = fmaxf(fmaf(acc[j0 + 3], inv, bv.w), 0.f);
    *(float4*)(out + (size_t)node * HC + cbase) = o;
}

extern "C" void kernel_launch(void* const* d_in, const int* in_sizes, int n_in,
                              void* d_out, int out_size, void* d_ws, size_t ws_size,
                              hipStream_t stream)
{
    const float* x    = (const float*)d_in[0];
    const int*   ei   = (const int*)d_in[1];
    const float* W    = (const float*)d_in[2];
    const float* attS = (const float*)d_in[3];
    const float* attD = (const float*)d_in[4];
    const float* bias = (const float*)d_in[5];
    float* out = (float*)d_out;

    const int N = in_sizes[0] / IN_CH;
    const int E = in_sizes[1] / 2;
    const int* esrc = ei;
    const int* edst = ei + E;

    unsigned short* h = (unsigned short*)d_ws;        // N*256 bf16
    float* aS = (float*)(h + (size_t)N * HC);         // N*8
    float* aD = aS + (size_t)N * HEADS;               // N*8
    int* counts  = (int*)(aD + (size_t)N * HEADS);    // N
    int* offsets = counts + N;                        // N+1
    int* cursor  = offsets + (N + 1);                 // N
    int* ssrc    = cursor + N;                        // E
    int* bsum    = ssrc + E;                          // <=64
    unsigned short* Wt = (unsigned short*)(bsum + 64);// 256*128 bf16

    const int nb = (N + 1023) / 1024;                 // 49 for N=50000 (<=64 req.)

    hipMemsetAsync(counts, 0, (size_t)N * sizeof(int), stream);

    gat_prep<<<(IN_CH * HC) / 256, 256, 0, stream>>>(W, Wt);
    gat_proj_mfma<<<(N + 15) / 16, 256, 0, stream>>>(x, Wt, attS, attD, h, aS, aD, N);
    gat_hist<<<(E / 4 + 255) / 256, 256, 0, stream>>>(edst, counts, E);
    gat_scan1<<<nb, 256, 0, stream>>>(counts, bsum, N);
    gat_scan2<<<1, 64, 0, stream>>>(bsum, offsets, nb, N);
    gat_scan3<<<nb, 256, 0, stream>>>(counts, bsum, offsets, cursor, N);
    gat_scatter<<<(E + 255) / 256, 256, 0, stream>>>(esrc, edst, cursor, ssrc, E);
    gat_agg<<<(N + 3) / 4, 256, 0, stream>>>(h, aS, aD, offsets, ssrc, bias, out, N);
}

// Round 5
// 196.979 us; speedup vs baseline: 1.9443x; 1.1081x over previous
//
#include <hip/hip_runtime.h>

#define IN_CH 128
#define OUT_CH 32
#define HEADS 8
#define HC 256            // HEADS*OUT_CH
#define NEG_SLOPE 0.2f

typedef __attribute__((ext_vector_type(8))) short short8;   // 8 bf16 = 4 VGPR
typedef __attribute__((ext_vector_type(4))) float f32x4;

// bf16 helpers (RNE)
__device__ __forceinline__ float bflo(unsigned u) { return __uint_as_float(u << 16); }
__device__ __forceinline__ float bfhi(unsigned u) { return __uint_as_float(u & 0xffff0000u); }
__device__ __forceinline__ float bf2f(unsigned short u) { return __uint_as_float(((unsigned)u) << 16); }
__device__ __forceinline__ unsigned short f2bf(float f) {
    unsigned u = __float_as_uint(f);
    u = (u + 0x7fffu + ((u >> 16) & 1u)) >> 16;
    return (unsigned short)u;
}

// ---------------- W transpose + f32->bf16 (once, 64 KB output) ----------------
__global__ __launch_bounds__(256)
void gat_prep(const float* __restrict__ W, unsigned short* __restrict__ Wt)
{
    const int idx = blockIdx.x * 256 + threadIdx.x;
    const int k = idx >> 8;
    const int col = idx & 255;
    Wt[col * IN_CH + k] = f2bf(W[idx]);
}

// ---------------- MFMA projection: h = x@W (bf16), + per-node logits ----------------
__global__ __launch_bounds__(256)
void gat_proj_mfma(const float* __restrict__ x, const unsigned short* __restrict__ Wt,
                   const float* __restrict__ attS, const float* __restrict__ attD,
                   unsigned short* __restrict__ h, float* __restrict__ aS,
                   float* __restrict__ aD, int N)
{
    __shared__ unsigned short xs[16 * 136];

    const int tid = threadIdx.x;
    const int lane = tid & 63;
    const int w = tid >> 6;
    const int row0 = blockIdx.x * 16;

    short8 bfr[4][4];
    {
        const unsigned short* wp = Wt + (size_t)(w * 64 + (lane & 15)) * IN_CH
                                      + ((lane >> 4) << 3);
#pragma unroll
        for (int i = 0; i < 4; ++i)
#pragma unroll
            for (int ks = 0; ks < 4; ++ks)
                bfr[ks][i] = *(const short8*)(wp + i * 16 * IN_CH + ks * 32);
    }

    {
        const int srow = tid >> 4;
        const int sseg = tid & 15;
        const int grow = row0 + srow;
        float4 v0 = make_float4(0.f, 0.f, 0.f, 0.f), v1 = v0;
        if (grow < N) {
            const float* xp = x + (size_t)grow * IN_CH + sseg * 8;
            v0 = *(const float4*)xp;
            v1 = *(const float4*)(xp + 4);
        }
        unsigned short* lp = xs + srow * 136 + sseg * 8;
        lp[0] = f2bf(v0.x); lp[1] = f2bf(v0.y); lp[2] = f2bf(v0.z); lp[3] = f2bf(v0.w);
        lp[4] = f2bf(v1.x); lp[5] = f2bf(v1.y); lp[6] = f2bf(v1.z); lp[7] = f2bf(v1.w);
    }
    __syncthreads();

    f32x4 acc[4] = {{0.f,0.f,0.f,0.f},{0.f,0.f,0.f,0.f},{0.f,0.f,0.f,0.f},{0.f,0.f,0.f,0.f}};
#pragma unroll
    for (int ks = 0; ks < 4; ++ks) {
        const short8 a = *(const short8*)&xs[(lane & 15) * 136 + ks * 32 + ((lane >> 4) << 3)];
#pragma unroll
        for (int i = 0; i < 4; ++i)
            acc[i] = __builtin_amdgcn_mfma_f32_16x16x32_bf16(a, bfr[ks][i], acc[i], 0, 0, 0);
    }

    // C/D map: col = lane&15, row = (lane>>4)*4 + reg   [m89-verified]
    const int rbase = (lane >> 4) << 2;
    float ps[2][4] = {{0.f,0.f,0.f,0.f},{0.f,0.f,0.f,0.f}};
    float pd[2][4] = {{0.f,0.f,0.f,0.f},{0.f,0.f,0.f,0.f}};
#pragma unroll
    for (int i = 0; i < 4; ++i) {
        const int col = w * 64 + i * 16 + (lane & 15);
        const int hp = i >> 1;
        const float asv = attS[(w * 2 + hp) * 32 + (i & 1) * 16 + (lane & 15)];
        const float adv = attD[(w * 2 + hp) * 32 + (i & 1) * 16 + (lane & 15)];
#pragma unroll
        for (int r = 0; r < 4; ++r) {
            const int grow = row0 + rbase + r;
            if (grow < N) h[(size_t)grow * HC + col] = f2bf(acc[i][r]);
            ps[hp][r] = fmaf(acc[i][r], asv, ps[hp][r]);
            pd[hp][r] = fmaf(acc[i][r], adv, pd[hp][r]);
        }
    }
#pragma unroll
    for (int off = 1; off < 16; off <<= 1) {
#pragma unroll
        for (int hp = 0; hp < 2; ++hp)
#pragma unroll
            for (int r = 0; r < 4; ++r) {
                ps[hp][r] += __shfl_xor(ps[hp][r], off, 64);
                pd[hp][r] += __shfl_xor(pd[hp][r], off, 64);
            }
    }
    if ((lane & 15) == 0) {
#pragma unroll
        for (int hp = 0; hp < 2; ++hp)
#pragma unroll
            for (int r = 0; r < 4; ++r) {
                const int grow = row0 + rbase + r;
                if (grow < N) {
                    aS[grow * HEADS + w * 2 + hp] = ps[hp][r];
                    aD[grow * HEADS + w * 2 + hp] = pd[hp][r];
                }
            }
    }
}

// ---------------- CSR build: histogram -> 3-phase scan -> scatter ----------------
__global__ __launch_bounds__(256)
void gat_hist(const int* __restrict__ dst, int* __restrict__ counts, int E)
{
    int i = (blockIdx.x * 256 + threadIdx.x) * 4;
    if (i + 3 < E) {
        const int4 d = *(const int4*)&dst[i];
        atomicAdd(&counts[d.x], 1);
        atomicAdd(&counts[d.y], 1);
        atomicAdd(&counts[d.z], 1);
        atomicAdd(&counts[d.w], 1);
    } else {
        for (; i < E; ++i) atomicAdd(&counts[dst[i]], 1);
    }
}

__global__ __launch_bounds__(256)
void gat_scan1(const int* __restrict__ counts, int* __restrict__ bsum, int n)
{
    __shared__ int ws[4];
    const int t = threadIdx.x;
    const int lane = t & 63;
    const int wid = t >> 6;
    const int idx = blockIdx.x * 1024 + t * 4;
    int4 v = {0, 0, 0, 0};
    if (idx + 3 < n) v = *(const int4*)&counts[idx];
    else {
        if (idx < n)     v.x = counts[idx];
        if (idx + 1 < n) v.y = counts[idx + 1];
        if (idx + 2 < n) v.z = counts[idx + 2];
    }
    int s4 = v.x + v.y + v.z + v.w;
#pragma unroll
    for (int off = 1; off < 64; off <<= 1) s4 += __shfl_xor(s4, off, 64);
    if (lane == 0) ws[wid] = s4;
    __syncthreads();
    if (t == 0) bsum[blockIdx.x] = ws[0] + ws[1] + ws[2] + ws[3];
}

__global__ void gat_scan2(int* __restrict__ bsum, int* __restrict__ offsets, int nb, int n)
{
    const int lane = threadIdx.x;
    const int v = (lane < nb) ? bsum[lane] : 0;
    int inc = v;
#pragma unroll
    for (int off = 1; off < 64; off <<= 1) {
        const int y = __shfl_up(inc, off, 64);
        if (lane >= off) inc += y;
    }
    if (lane < nb) bsum[lane] = inc - v;
    if (lane == 63) offsets[n] = inc;
}

__global__ __launch_bounds__(256)
void gat_scan3(const int* __restrict__ counts, const int* __restrict__ bsum,
               int* __restrict__ offsets, int* __restrict__ cursor, int n)
{
    __shared__ int wsums[4];
    const int t = threadIdx.x;
    const int lane = t & 63;
    const int wid = t >> 6;
    const int idx = blockIdx.x * 1024 + t * 4;
    int4 v = {0, 0, 0, 0};
    if (idx + 3 < n) v = *(const int4*)&counts[idx];
    else {
        if (idx < n)     v.x = counts[idx];
        if (idx + 1 < n) v.y = counts[idx + 1];
        if (idx + 2 < n) v.z = counts[idx + 2];
    }
    const int s4 = v.x + v.y + v.z + v.w;
    int inc = s4;
#pragma unroll
    for (int off = 1; off < 64; off <<= 1) {
        const int y = __shfl_up(inc, off, 64);
        if (lane >= off) inc += y;
    }
    if (lane == 63) wsums[wid] = inc;
    __syncthreads();
    int wbase = 0;
    for (int i = 0; i < wid; ++i) wbase += wsums[i];
    const int base = bsum[blockIdx.x] + wbase + (inc - s4);
    int4 o;
    o.x = base;
    o.y = base + v.x;
    o.z = o.y + v.y;
    o.w = o.z + v.z;
    if (idx + 3 < n) {
        *(int4*)&offsets[idx] = o;
        *(int4*)&cursor[idx] = o;
    } else {
        if (idx < n)     { offsets[idx] = o.x;     cursor[idx] = o.x; }
        if (idx + 1 < n) { offsets[idx + 1] = o.y; cursor[idx + 1] = o.y; }
        if (idx + 2 < n) { offsets[idx + 2] = o.z; cursor[idx + 2] = o.z; }
    }
}

// scatter + per-edge attention weight precompute:
// ealpha[pos][head] = exp(leaky_relu(aS[s]+aD[d])) in bf16
__global__ __launch_bounds__(256)
void gat_scatter(const int* __restrict__ src, const int* __restrict__ dst,
                 int* __restrict__ cursor, int* __restrict__ ssrc,
                 unsigned short* __restrict__ ealpha,
                 const float* __restrict__ aS, const float* __restrict__ aD, int E)
{
    const int e = blockIdx.x * 256 + threadIdx.x;
    if (e >= E) return;
    const int s = src[e];
    const int d = dst[e];
    const int pos = atomicAdd(&cursor[d], 1);
    ssrc[pos] = s;
    const float4 s0 = *(const float4*)(aS + (size_t)s * HEADS);
    const float4 s1 = *(const float4*)(aS + (size_t)s * HEADS + 4);
    const float4 d0 = *(const float4*)(aD + (size_t)d * HEADS);
    const float4 d1 = *(const float4*)(aD + (size_t)d * HEADS + 4);
    float lg[8] = { s0.x + d0.x, s0.y + d0.y, s0.z + d0.z, s0.w + d0.w,
                    s1.x + d1.x, s1.y + d1.y, s1.z + d1.z, s1.w + d1.w };
    short8 al;
#pragma unroll
    for (int k = 0; k < 8; ++k) {
        const float v = lg[k] > 0.f ? lg[k] : NEG_SLOPE * lg[k];
        al[k] = (short)f2bf(__expf(v));
    }
    *(short8*)(ealpha + (size_t)pos * HEADS) = al;
}

// ---------------- Per-node aggregation ----------------
// One wave per node; 4 edges per iteration (2 per 32-lane half, uint4 loads).
// Attention weights come from the precomputed ealpha stream, so the only
// dependent load in the loop is the h row itself; next iteration's indices
// and weights are prefetched with clamped branch-free loads.
__global__ __launch_bounds__(256)
void gat_agg(const unsigned short* __restrict__ h,
             const float* __restrict__ aS, const float* __restrict__ aD,
             const int* __restrict__ offsets, const int* __restrict__ ssrc,
             const unsigned short* __restrict__ ealpha,
             const float* __restrict__ bias, float* __restrict__ out, int N)
{
    const int t = threadIdx.x;
    const int lane = t & 63;
    const int node = blockIdx.x * 4 + (t >> 6);
    if (node >= N) return;

    const int half = lane >> 5;
    const int hl = lane & 31;
    const int head = hl >> 2;                  // 4 lanes per head
    const int ch = head * 32 + (hl & 3) * 8;   // 8 channels per lane

    float sum;
    float acc[8];
    {   // self loop (half 0 only)
        float lg0 = aS[node * HEADS + head] + aD[node * HEADS + head];
        lg0 = (lg0 > 0.f) ? lg0 : NEG_SLOPE * lg0;
        const float w0 = half ? 0.f : __expf(lg0);
        sum = w0;
        const uint4 hv = *(const uint4*)(h + (size_t)node * HC + ch);
        acc[0] = w0 * bflo(hv.x); acc[1] = w0 * bfhi(hv.x);
        acc[2] = w0 * bflo(hv.y); acc[3] = w0 * bfhi(hv.y);
        acc[4] = w0 * bflo(hv.z); acc[5] = w0 * bfhi(hv.z);
        acc[6] = w0 * bflo(hv.w); acc[7] = w0 * bfhi(hv.w);
    }

    const int beg = offsets[node];
    const int end = offsets[node + 1];
    const int last = end - 1;

    int s0 = node, s1 = node;
    float a0 = 0.f, a1 = 0.f;
    if (beg < end) {   // wave-uniform branch
        const int e0 = beg + half * 2;
        const int e1 = e0 + 1;
        const int c0 = min(e0, last), c1 = min(e1, last);
        s0 = ssrc[c0]; s1 = ssrc[c1];
        a0 = bf2f(ealpha[(size_t)c0 * HEADS + head]);
        a1 = bf2f(ealpha[(size_t)c1 * HEADS + head]);
        if (e0 > last) { s0 = node; a0 = 0.f; }
        if (e1 > last) { s1 = node; a1 = 0.f; }
    }

#pragma unroll 2
    for (int base = beg; base < end; base += 4) {
        // prefetch next quad's indices/weights (branch-free, clamped)
        const int n0 = base + 4 + half * 2;
        const int n1 = n0 + 1;
        const int c0 = min(n0, last), c1 = min(n1, last);
        int t0 = ssrc[c0];
        int t1 = ssrc[c1];
        float b0 = bf2f(ealpha[(size_t)c0 * HEADS + head]);
        float b1 = bf2f(ealpha[(size_t)c1 * HEADS + head]);
        if (n0 > last) { t0 = node; b0 = 0.f; }
        if (n1 > last) { t1 = node; b1 = 0.f; }

        const uint4 v0 = *(const uint4*)(h + (size_t)s0 * HC + ch);
        const uint4 v1 = *(const uint4*)(h + (size_t)s1 * HC + ch);
        sum += a0 + a1;
        acc[0] = fmaf(a0, bflo(v0.x), acc[0]);
        acc[1] = fmaf(a0, bfhi(v0.x), acc[1]);
        acc[2] = fmaf(a0, bflo(v0.y), acc[2]);
        acc[3] = fmaf(a0, bfhi(v0.y), acc[3]);
        acc[4] = fmaf(a0, bflo(v0.z), acc[4]);
        acc[5] = fmaf(a0, bfhi(v0.z), acc[5]);
        acc[6] = fmaf(a0, bflo(v0.w), acc[6]);
        acc[7] = fmaf(a0, bfhi(v0.w), acc[7]);
        acc[0] = fmaf(a1, bflo(v1.x), acc[0]);
        acc[1] = fmaf(a1, bfhi(v1.x), acc[1]);
        acc[2] = fmaf(a1, bflo(v1.y), acc[2]);
        acc[3] = fmaf(a1, bfhi(v1.y), acc[3]);
        acc[4] = fmaf(a1, bflo(v1.z), acc[4]);
        acc[5] = fmaf(a1, bfhi(v1.z), acc[5]);
        acc[6] = fmaf(a1, bflo(v1.w), acc[6]);
        acc[7] = fmaf(a1, bfhi(v1.w), acc[7]);
        s0 = t0; s1 = t1; a0 = b0; a1 = b1;
    }

    // combine halves
#pragma unroll
    for (int j = 0; j < 8; ++j) acc[j] += __shfl_xor(acc[j], 32, 64);
    sum += __shfl_xor(sum, 32, 64);

    const float inv = 1.f / (sum + 1e-16f);
    const int cbase = ch + half * 4;
    const int j0 = half * 4;
    const float4 bv = *(const float4*)(bias + cbase);
    float4 o;
    o.x = fmaxf(fmaf(acc[j0 + 0], inv, bv.x), 0.f);
    o.y = fmaxf(fmaf(acc[j0 + 1], inv, bv.y), 0.f);
    o.z = fmaxf(fmaf(acc[j0 + 2], inv, bv.z), 0.f);
    o.w = fmaxf(fmaf(acc[j0 + 3], inv, bv.w), 0.f);
    *(float4*)(out + (size_t)node * HC + cbase) = o;
}

extern "C" void kernel_launch(void* const* d_in, const int* in_sizes, int n_in,
                              void* d_out, int out_size, void* d_ws, size_t ws_size,
                              hipStream_t stream)
{
    const float* x    = (const float*)d_in[0];
    const int*   ei   = (const int*)d_in[1];
    const float* W    = (const float*)d_in[2];
    const float* attS = (const float*)d_in[3];
    const float* attD = (const float*)d_in[4];
    const float* bias = (const float*)d_in[5];
    float* out = (float*)d_out;

    const int N = in_sizes[0] / IN_CH;
    const int E = in_sizes[1] / 2;
    const int* esrc = ei;
    const int* edst = ei + E;

    unsigned short* h = (unsigned short*)d_ws;        // N*256 bf16
    float* aS = (float*)(h + (size_t)N * HC);         // N*8
    float* aD = aS + (size_t)N * HEADS;               // N*8
    int* counts  = (int*)(aD + (size_t)N * HEADS);    // N
    int* offsets = counts + N;                        // N+1 (padded to N+4 for alignment)
    int* cursor  = offsets + (N + 4);                 // N
    int* ssrc    = cursor + N;                        // E
    int* bsum    = ssrc + E;                          // <=64
    unsigned short* Wt = (unsigned short*)(bsum + 64);// 256*128 bf16
    unsigned short* ealpha = Wt + IN_CH * HC;         // E*8 bf16

    const int nb = (N + 1023) / 1024;

    hipMemsetAsync(counts, 0, (size_t)N * sizeof(int), stream);

    gat_prep<<<(IN_CH * HC) / 256, 256, 0, stream>>>(W, Wt);
    gat_proj_mfma<<<(N + 15) / 16, 256, 0, stream>>>(x, Wt, attS, attD, h, aS, aD, N);
    gat_hist<<<(E / 4 + 255) / 256, 256, 0, stream>>>(edst, counts, E);
    gat_scan1<<<nb, 256, 0, stream>>>(counts, bsum, N);
    gat_scan2<<<1, 64, 0, stream>>>(bsum, offsets, nb, N);
    gat_scan3<<<nb, 256, 0, stream>>>(counts, bsum, offsets, cursor, N);
    gat_scatter<<<(E + 255) / 256, 256, 0, stream>>>(esrc, edst, cursor, ssrc, ealpha, aS, aD, E);
    gat_agg<<<(N + 3) / 4, 256, 0, stream>>>(h, aS, aD, offsets, ssrc, ealpha, bias, out, N);
}

// Round 6
// 189.989 us; speedup vs baseline: 2.0159x; 1.0368x over previous
//
#include <hip/hip_runtime.h>

#define IN_CH 128
#define OUT_CH 32
#define HEADS 8
#define HC 256            // HEADS*OUT_CH
#define NEG_SLOPE 0.2f

typedef __attribute__((ext_vector_type(8))) short short8;   // 8 bf16 = 4 VGPR
typedef __attribute__((ext_vector_type(4))) float f32x4;

// bf16 helpers (RNE)
__device__ __forceinline__ float bflo(unsigned u) { return __uint_as_float(u << 16); }
__device__ __forceinline__ float bfhi(unsigned u) { return __uint_as_float(u & 0xffff0000u); }
__device__ __forceinline__ float bf2f(unsigned short u) { return __uint_as_float(((unsigned)u) << 16); }
__device__ __forceinline__ unsigned short f2bf(float f) {
    unsigned u = __float_as_uint(f);
    u = (u + 0x7fffu + ((u >> 16) & 1u)) >> 16;
    return (unsigned short)u;
}

// ---------- W transpose + f32->bf16, and zero the histogram counts ----------
__global__ __launch_bounds__(256)
void gat_prep(const float* __restrict__ W, unsigned short* __restrict__ Wt,
              int* __restrict__ counts, int n)
{
    const int idx = blockIdx.x * 256 + threadIdx.x;   // 32768 threads
    const int k = idx >> 8;
    const int col = idx & 255;
    Wt[col * IN_CH + k] = f2bf(W[idx]);
    for (int i = idx; i < n; i += 32768) counts[i] = 0;
}

// ---------------- MFMA projection: h = x@W (bf16), + per-node logits ----------------
// 32 rows x 256 cols per block (4 waves); wave w owns cols [w*64, w*64+64).
__global__ __launch_bounds__(256)
void gat_proj_mfma(const float* __restrict__ x, const unsigned short* __restrict__ Wt,
                   const float* __restrict__ attS, const float* __restrict__ attD,
                   unsigned short* __restrict__ h, float* __restrict__ aS,
                   float* __restrict__ aD, int N)
{
    __shared__ unsigned short xs[32 * 136];

    const int tid = threadIdx.x;
    const int lane = tid & 63;
    const int w = tid >> 6;
    const int row0 = blockIdx.x * 32;

    short8 bfr[4][4];   // [ks][i] B fragments, preloaded once per block
    {
        const unsigned short* wp = Wt + (size_t)(w * 64 + (lane & 15)) * IN_CH
                                      + ((lane >> 4) << 3);
#pragma unroll
        for (int i = 0; i < 4; ++i)
#pragma unroll
            for (int ks = 0; ks < 4; ++ks)
                bfr[ks][i] = *(const short8*)(wp + i * 16 * IN_CH + ks * 32);
    }

    // stage 32x128 x-tile -> LDS bf16 (each thread 2 row-segments)
#pragma unroll
    for (int u = 0; u < 2; ++u) {
        const int unit = tid + u * 256;
        const int srow = unit >> 4;
        const int sseg = unit & 15;
        const int grow = row0 + srow;
        float4 v0 = make_float4(0.f, 0.f, 0.f, 0.f), v1 = v0;
        if (grow < N) {
            const float* xp = x + (size_t)grow * IN_CH + sseg * 8;
            v0 = *(const float4*)xp;
            v1 = *(const float4*)(xp + 4);
        }
        unsigned short* lp = xs + srow * 136 + sseg * 8;
        lp[0] = f2bf(v0.x); lp[1] = f2bf(v0.y); lp[2] = f2bf(v0.z); lp[3] = f2bf(v0.w);
        lp[4] = f2bf(v1.x); lp[5] = f2bf(v1.y); lp[6] = f2bf(v1.z); lp[7] = f2bf(v1.w);
    }
    __syncthreads();

    f32x4 acc[2][4];
#pragma unroll
    for (int m = 0; m < 2; ++m)
#pragma unroll
        for (int i = 0; i < 4; ++i) acc[m][i] = (f32x4){0.f, 0.f, 0.f, 0.f};

#pragma unroll
    for (int ks = 0; ks < 4; ++ks) {
#pragma unroll
        for (int m = 0; m < 2; ++m) {
            const short8 a = *(const short8*)&xs[((lane & 15) + m * 16) * 136
                                                 + ks * 32 + ((lane >> 4) << 3)];
#pragma unroll
            for (int i = 0; i < 4; ++i)
                acc[m][i] = __builtin_amdgcn_mfma_f32_16x16x32_bf16(a, bfr[ks][i], acc[m][i], 0, 0, 0);
        }
    }

    // C/D map: col = lane&15, row = (lane>>4)*4 + reg   [m89-verified]
    const int rbase = (lane >> 4) << 2;
    float ps[2][2][4], pd[2][2][4];
#pragma unroll
    for (int m = 0; m < 2; ++m)
#pragma unroll
        for (int hp = 0; hp < 2; ++hp)
#pragma unroll
            for (int r = 0; r < 4; ++r) { ps[m][hp][r] = 0.f; pd[m][hp][r] = 0.f; }

#pragma unroll
    for (int i = 0; i < 4; ++i) {
        const int col = w * 64 + i * 16 + (lane & 15);
        const int hp = i >> 1;
        const float asv = attS[(w * 2 + hp) * 32 + (i & 1) * 16 + (lane & 15)];
        const float adv = attD[(w * 2 + hp) * 32 + (i & 1) * 16 + (lane & 15)];
#pragma unroll
        for (int m = 0; m < 2; ++m) {
#pragma unroll
            for (int r = 0; r < 4; ++r) {
                const int grow = row0 + m * 16 + rbase + r;
                if (grow < N) h[(size_t)grow * HC + col] = f2bf(acc[m][i][r]);
                ps[m][hp][r] = fmaf(acc[m][i][r], asv, ps[m][hp][r]);
                pd[m][hp][r] = fmaf(acc[m][i][r], adv, pd[m][hp][r]);
            }
        }
    }
#pragma unroll
    for (int off = 1; off < 16; off <<= 1) {
#pragma unroll
        for (int m = 0; m < 2; ++m)
#pragma unroll
            for (int hp = 0; hp < 2; ++hp)
#pragma unroll
                for (int r = 0; r < 4; ++r) {
                    ps[m][hp][r] += __shfl_xor(ps[m][hp][r], off, 64);
                    pd[m][hp][r] += __shfl_xor(pd[m][hp][r], off, 64);
                }
    }
    if ((lane & 15) == 0) {
#pragma unroll
        for (int m = 0; m < 2; ++m)
#pragma unroll
            for (int hp = 0; hp < 2; ++hp)
#pragma unroll
                for (int r = 0; r < 4; ++r) {
                    const int grow = row0 + m * 16 + rbase + r;
                    if (grow < N) {
                        aS[grow * HEADS + w * 2 + hp] = ps[m][hp][r];
                        aD[grow * HEADS + w * 2 + hp] = pd[m][hp][r];
                    }
                }
    }
}

// ---------------- CSR build: histogram -> scan -> scatter ----------------
__global__ __launch_bounds__(256)
void gat_hist(const int* __restrict__ dst, int* __restrict__ counts, int E)
{
    int i = (blockIdx.x * 256 + threadIdx.x) * 4;
    if (i + 3 < E) {
        const int4 d = *(const int4*)&dst[i];
        atomicAdd(&counts[d.x], 1);
        atomicAdd(&counts[d.y], 1);
        atomicAdd(&counts[d.z], 1);
        atomicAdd(&counts[d.w], 1);
    } else {
        for (; i < E; ++i) atomicAdd(&counts[dst[i]], 1);
    }
}

// phase 1: per-1024-chunk sums
__global__ __launch_bounds__(256)
void gat_scan1(const int* __restrict__ counts, int* __restrict__ bsum, int n)
{
    __shared__ int ws[4];
    const int t = threadIdx.x;
    const int lane = t & 63;
    const int wid = t >> 6;
    const int idx = blockIdx.x * 1024 + t * 4;
    int4 v = {0, 0, 0, 0};
    if (idx + 3 < n) v = *(const int4*)&counts[idx];
    else {
        if (idx < n)     v.x = counts[idx];
        if (idx + 1 < n) v.y = counts[idx + 1];
        if (idx + 2 < n) v.z = counts[idx + 2];
    }
    int s4 = v.x + v.y + v.z + v.w;
#pragma unroll
    for (int off = 1; off < 64; off <<= 1) s4 += __shfl_xor(s4, off, 64);
    if (lane == 0) ws[wid] = s4;
    __syncthreads();
    if (t == 0) bsum[blockIdx.x] = ws[0] + ws[1] + ws[2] + ws[3];
}

// phase 2: per-chunk scan; each block re-scans bsum (nb<=64) in wave 0
__global__ __launch_bounds__(256)
void gat_scan3(const int* __restrict__ counts, const int* __restrict__ bsum,
               int* __restrict__ offsets, int* __restrict__ cursor,
               int n, int nb, int E)
{
    __shared__ int wsums[4];
    __shared__ int bbase_s;
    const int t = threadIdx.x;
    const int lane = t & 63;
    const int wid = t >> 6;

    if (t < 64) {   // wave 0: exclusive prefix of bsum at index blockIdx.x
        const int v = (t < nb) ? bsum[t] : 0;
        int inc = v;
#pragma unroll
        for (int off = 1; off < 64; off <<= 1) {
            const int y = __shfl_up(inc, off, 64);
            if (t >= off) inc += y;
        }
        const int myv   = __shfl(v, blockIdx.x, 64);
        const int myinc = __shfl(inc, blockIdx.x, 64);
        if (t == 0) bbase_s = myinc - myv;
    }

    const int idx = blockIdx.x * 1024 + t * 4;
    int4 v = {0, 0, 0, 0};
    if (idx + 3 < n) v = *(const int4*)&counts[idx];
    else {
        if (idx < n)     v.x = counts[idx];
        if (idx + 1 < n) v.y = counts[idx + 1];
        if (idx + 2 < n) v.z = counts[idx + 2];
    }
    const int s4 = v.x + v.y + v.z + v.w;
    int inc = s4;
#pragma unroll
    for (int off = 1; off < 64; off <<= 1) {
        const int y = __shfl_up(inc, off, 64);
        if (lane >= off) inc += y;
    }
    if (lane == 63) wsums[wid] = inc;
    __syncthreads();
    int wbase = 0;
    for (int i = 0; i < wid; ++i) wbase += wsums[i];
    const int base = bbase_s + wbase + (inc - s4);
    int4 o;
    o.x = base;
    o.y = base + v.x;
    o.z = o.y + v.y;
    o.w = o.z + v.z;
    if (idx + 3 < n) {
        *(int4*)&offsets[idx] = o;
        *(int4*)&cursor[idx] = o;
    } else {
        if (idx < n)     { offsets[idx] = o.x;     cursor[idx] = o.x; }
        if (idx + 1 < n) { offsets[idx + 1] = o.y; cursor[idx + 1] = o.y; }
        if (idx + 2 < n) { offsets[idx + 2] = o.z; cursor[idx + 2] = o.z; }
    }
    if (blockIdx.x == 0 && t == 0) offsets[n] = E;
}

// scatter + per-edge attention weight precompute:
// ealpha[pos][head] = exp(leaky_relu(aS[s]+aD[d])) in bf16
__global__ __launch_bounds__(256)
void gat_scatter(const int* __restrict__ src, const int* __restrict__ dst,
                 int* __restrict__ cursor, int* __restrict__ ssrc,
                 unsigned short* __restrict__ ealpha,
                 const float* __restrict__ aS, const float* __restrict__ aD, int E)
{
    const int e = blockIdx.x * 256 + threadIdx.x;
    if (e >= E) return;
    const int s = src[e];
    const int d = dst[e];
    const int pos = atomicAdd(&cursor[d], 1);
    ssrc[pos] = s;
    const float4 s0 = *(const float4*)(aS + (size_t)s * HEADS);
    const float4 s1 = *(const float4*)(aS + (size_t)s * HEADS + 4);
    const float4 d0 = *(const float4*)(aD + (size_t)d * HEADS);
    const float4 d1 = *(const float4*)(aD + (size_t)d * HEADS + 4);
    float lg[8] = { s0.x + d0.x, s0.y + d0.y, s0.z + d0.z, s0.w + d0.w,
                    s1.x + d1.x, s1.y + d1.y, s1.z + d1.z, s1.w + d1.w };
    short8 al;
#pragma unroll
    for (int k = 0; k < 8; ++k) {
        const float v = lg[k] > 0.f ? lg[k] : NEG_SLOPE * lg[k];
        al[k] = (short)f2bf(__expf(v));
    }
    *(short8*)(ealpha + (size_t)pos * HEADS) = al;
}

// ---------------- Per-node aggregation ----------------
// One wave per node; 8 edges per iteration (4 per 32-lane half, uint4 loads),
// next iteration's indices/weights prefetched branch-free -> 8 independent
// h-row fetches in flight per wave.
__global__ __launch_bounds__(256)
void gat_agg(const unsigned short* __restrict__ h,
             const float* __restrict__ aS, const float* __restrict__ aD,
             const int* __restrict__ offsets, const int* __restrict__ ssrc,
             const unsigned short* __restrict__ ealpha,
             const float* __restrict__ bias, float* __restrict__ out, int N)
{
    const int t = threadIdx.x;
    const int lane = t & 63;
    const int node = blockIdx.x * 4 + (t >> 6);
    if (node >= N) return;

    const int half = lane >> 5;
    const int hl = lane & 31;
    const int head = hl >> 2;                  // 4 lanes per head
    const int ch = head * 32 + (hl & 3) * 8;   // 8 channels per lane

    float sum;
    float acc[8];
    {   // self loop (half 0 only)
        float lg0 = aS[node * HEADS + head] + aD[node * HEADS + head];
        lg0 = (lg0 > 0.f) ? lg0 : NEG_SLOPE * lg0;
        const float w0 = half ? 0.f : __expf(lg0);
        sum = w0;
        const uint4 hv = *(const uint4*)(h + (size_t)node * HC + ch);
        acc[0] = w0 * bflo(hv.x); acc[1] = w0 * bfhi(hv.x);
        acc[2] = w0 * bflo(hv.y); acc[3] = w0 * bfhi(hv.y);
        acc[4] = w0 * bflo(hv.z); acc[5] = w0 * bfhi(hv.z);
        acc[6] = w0 * bflo(hv.w); acc[7] = w0 * bfhi(hv.w);
    }

    const int beg = offsets[node];
    const int end = offsets[node + 1];
    const int last = end - 1;

    int sE[4];
    float aE[4];
#pragma unroll
    for (int j = 0; j < 4; ++j) { sE[j] = node; aE[j] = 0.f; }

    if (beg < end) {   // wave-uniform
#pragma unroll
        for (int j = 0; j < 4; ++j) {
            const int e = beg + half * 4 + j;
            const int c = min(e, last);
            int s = ssrc[c];
            float a = bf2f(ealpha[(size_t)c * HEADS + head]);
            if (e > last) { s = node; a = 0.f; }
            sE[j] = s; aE[j] = a;
        }
    }

    for (int base = beg; base < end; base += 8) {
        // prefetch next 8 (branch-free, clamped)
        int tS[4]; float tA[4];
#pragma unroll
        for (int j = 0; j < 4; ++j) {
            const int e = base + 8 + half * 4 + j;
            const int c = min(e, last);
            int s = ssrc[c];
            float a = bf2f(ealpha[(size_t)c * HEADS + head]);
            if (e > last) { s = node; a = 0.f; }
            tS[j] = s; tA[j] = a;
        }
        // consume current 4 (per half) — 4 independent uint4 loads
        uint4 v[4];
#pragma unroll
        for (int j = 0; j < 4; ++j)
            v[j] = *(const uint4*)(h + (size_t)sE[j] * HC + ch);
#pragma unroll
        for (int j = 0; j < 4; ++j) {
            const float a = aE[j];
            sum += a;
            acc[0] = fmaf(a, bflo(v[j].x), acc[0]);
            acc[1] = fmaf(a, bfhi(v[j].x), acc[1]);
            acc[2] = fmaf(a, bflo(v[j].y), acc[2]);
            acc[3] = fmaf(a, bfhi(v[j].y), acc[3]);
            acc[4] = fmaf(a, bflo(v[j].z), acc[4]);
            acc[5] = fmaf(a, bfhi(v[j].z), acc[5]);
            acc[6] = fmaf(a, bflo(v[j].w), acc[6]);
            acc[7] = fmaf(a, bfhi(v[j].w), acc[7]);
        }
#pragma unroll
        for (int j = 0; j < 4; ++j) { sE[j] = tS[j]; aE[j] = tA[j]; }
    }

    // combine halves
#pragma unroll
    for (int j = 0; j < 8; ++j) acc[j] += __shfl_xor(acc[j], 32, 64);
    sum += __shfl_xor(sum, 32, 64);

    const float inv = 1.f / (sum + 1e-16f);
    const int cbase = ch + half * 4;
    const int j0 = half * 4;
    const float4 bv = *(const float4*)(bias + cbase);
    float4 o;
    o.x = fmaxf(fmaf(acc[j0 + 0], inv, bv.x), 0.f);
    o.y = fmaxf(fmaf(acc[j0 + 1], inv, bv.y), 0.f);
    o.z = fmaxf(fmaf(acc[j0 + 2], inv, bv.z), 0.f);
    o.w = fmaxf(fmaf(acc[j0 + 3], inv, bv.w), 0.f);
    *(float4*)(out + (size_t)node * HC + cbase) = o;
}

extern "C" void kernel_launch(void* const* d_in, const int* in_sizes, int n_in,
                              void* d_out, int out_size, void* d_ws, size_t ws_size,
                              hipStream_t stream)
{
    const float* x    = (const float*)d_in[0];
    const int*   ei   = (const int*)d_in[1];
    const float* W    = (const float*)d_in[2];
    const float* attS = (const float*)d_in[3];
    const float* attD = (const float*)d_in[4];
    const float* bias = (const float*)d_in[5];
    float* out = (float*)d_out;

    const int N = in_sizes[0] / IN_CH;
    const int E = in_sizes[1] / 2;
    const int* esrc = ei;
    const int* edst = ei + E;

    unsigned short* h = (unsigned short*)d_ws;        // N*256 bf16
    float* aS = (float*)(h + (size_t)N * HC);         // N*8
    float* aD = aS + (size_t)N * HEADS;               // N*8
    int* counts  = (int*)(aD + (size_t)N * HEADS);    // N
    int* offsets = counts + N;                        // N+1 (padded to N+4)
    int* cursor  = offsets + (N + 4);                 // N
    int* ssrc    = cursor + N;                        // E
    int* bsum    = ssrc + E;                          // <=64
    unsigned short* Wt = (unsigned short*)(bsum + 64);// 256*128 bf16
    unsigned short* ealpha = Wt + IN_CH * HC;         // E*8 bf16

    const int nb = (N + 1023) / 1024;                 // 49 (must be <=64)

    gat_prep<<<(IN_CH * HC) / 256, 256, 0, stream>>>(W, Wt, counts, N);
    gat_proj_mfma<<<(N + 31) / 32, 256, 0, stream>>>(x, Wt, attS, attD, h, aS, aD, N);
    gat_hist<<<(E / 4 + 255) / 256, 256, 0, stream>>>(edst, counts, E);
    gat_scan1<<<nb, 256, 0, stream>>>(counts, bsum, N);
    gat_scan3<<<nb, 256, 0, stream>>>(counts, bsum, offsets, cursor, N, nb, E);
    gat_scatter<<<(E + 255) / 256, 256, 0, stream>>>(esrc, edst, cursor, ssrc, ealpha, aS, aD, E);
    gat_agg<<<(N + 3) / 4, 256, 0, stream>>>(h, aS, aD, offsets, ssrc, ealpha, bias, out, N);
}